// Round 9
// baseline (460.203 us; speedup 1.0000x reference)
//
#include <hip/hip_runtime.h>
#include <hip/hip_bf16.h>

typedef int   i32x4 __attribute__((ext_vector_type(4)));
typedef unsigned int   u32;
typedef unsigned short u16;
typedef signed char    i8;

#define TOKENS 8192
#define NDIM   4096
#define KDIM   4096
#define BK     64            // K per tile, in i8 elements
#define NKT    (KDIM / BK)   // 64 K-tiles

// ---------------------------------------------------------------------------
// Kernel 1: FWHT each row of x (4096 f32), quantize row to int8, per-row scale.
// (unchanged, validated)
// ---------------------------------------------------------------------------
__global__ __launch_bounds__(64)
void fwht_rows_q8(const float* __restrict__ x, i8* __restrict__ xq,
                  float* __restrict__ xscale) {
  const int row = blockIdx.x;
  const int l   = threadIdx.x;

  const float4* xv = reinterpret_cast<const float4*>(x + (size_t)row * KDIM) + l * 16;
  float v[64];
#pragma unroll
  for (int j = 0; j < 16; ++j) {
    float4 f = xv[j];
    v[4*j+0] = f.x; v[4*j+1] = f.y; v[4*j+2] = f.z; v[4*j+3] = f.w;
  }

#pragma unroll
  for (int h = 1; h < 64; h <<= 1) {
#pragma unroll
    for (int j = 0; j < 64; ++j) {
      if ((j & h) == 0) {
        float a = v[j], b = v[j + h];
        v[j] = a + b; v[j + h] = a - b;
      }
    }
  }

#pragma unroll
  for (int m = 1; m < 64; m <<= 1) {
    const bool up = (l & m) != 0;
#pragma unroll
    for (int j = 0; j < 64; ++j) {
      float p = __shfl_xor(v[j], m, 64);
      v[j] = up ? (p - v[j]) : (v[j] + p);
    }
  }

  float mxu = 0.f;
#pragma unroll
  for (int j = 0; j < 64; ++j) mxu = fmaxf(mxu, fabsf(v[j]));
#pragma unroll
  for (int m = 1; m < 64; m <<= 1) mxu = fmaxf(mxu, __shfl_xor(mxu, m, 64));
  mxu = fmaxf(mxu, 1e-30f);
  const float inv = 127.0f / mxu;

  i8* orow = xq + (size_t)row * KDIM + l * 64;
#pragma unroll
  for (int g = 0; g < 4; ++g) {
    u32 w[4];
#pragma unroll
    for (int q4 = 0; q4 < 4; ++q4) {
      int b0 = __float2int_rn(v[g*16+q4*4+0] * inv);
      int b1 = __float2int_rn(v[g*16+q4*4+1] * inv);
      int b2 = __float2int_rn(v[g*16+q4*4+2] * inv);
      int b3 = __float2int_rn(v[g*16+q4*4+3] * inv);
      b0 = min(127, max(-127, b0)); b1 = min(127, max(-127, b1));
      b2 = min(127, max(-127, b2)); b3 = min(127, max(-127, b3));
      w[q4] = (u32)(b0 & 0xff) | ((u32)(b1 & 0xff) << 8) |
              ((u32)(b2 & 0xff) << 16) | ((u32)(b3 & 0xff) << 24);
    }
    uint4 pk; pk.x = w[0]; pk.y = w[1]; pk.z = w[2]; pk.w = w[3];
    *reinterpret_cast<uint4*>(orow + g * 16) = pk;
  }
  if (l == 0) xscale[row] = mxu * (0.015625f / 127.0f);  // (mx/64)/127
}

// ---------------------------------------------------------------------------
// Kernel 2: pack Q (int32 in [-127,127]) to int8. (unchanged, validated)
// ---------------------------------------------------------------------------
__device__ __forceinline__ u32 pack4(int4 q) {
  return (u32)(q.x & 0xff) | ((u32)(q.y & 0xff) << 8) |
         ((u32)(q.z & 0xff) << 16) | ((u32)(q.w & 0xff) << 24);
}
__global__ __launch_bounds__(256)
void qpack(const int* __restrict__ Q, i8* __restrict__ W8) {
  const size_t idx = ((size_t)blockIdx.x * 256 + threadIdx.x) * 16;
  int4 a = *reinterpret_cast<const int4*>(Q + idx);
  int4 b = *reinterpret_cast<const int4*>(Q + idx + 4);
  int4 c = *reinterpret_cast<const int4*>(Q + idx + 8);
  int4 d = *reinterpret_cast<const int4*>(Q + idx + 12);
  uint4 pk; pk.x = pack4(a); pk.y = pack4(b); pk.z = pack4(c); pk.w = pack4(d);
  *reinterpret_cast<uint4*>(W8 + idx) = pk;
}

// ---------------------------------------------------------------------------
// Kernel 3: int8 GEMM, DIRECT-TO-REGISTER (no LDS, no barriers).
// BM=BN=256, BK=64, 8 waves (2Mx4N), per-wave 128x64, acc[8][4] (128 AGPR).
// Each wave loads its MFMA fragments straight from row-major xq/W8:
//   lane l -> row (l&15), kbytes (l>>4)*16  => 16 fully-used 64B transactions
// Double-buffered fragment sets (a0/b0, a1/b1), per-wave vmcnt(12) counting:
// use tile t while tile t+1's 12 loads are in flight; issue t+2 after MFMA.
// Waves drift freely -> vmem pipe overlaps matrix pipe across waves.
// ---------------------------------------------------------------------------
__global__ __launch_bounds__(512, 2)
void gemm_dr_i8(const i8* __restrict__ A, const i8* __restrict__ B,
                const float* __restrict__ xscale, const float* __restrict__ s,
                const float* __restrict__ bias, float* __restrict__ C) {
  const int th   = threadIdx.x;
  const int wave = th >> 6;
  const int lane = th & 63;

  // L2-locality mapping (bijective, 512 blocks)
  const int b0 = blockIdx.x;
  const int xc = b0 & 7;
  const int i  = b0 >> 3;
  const int mt = i >> 1;
  const int nt = xc * 2 + (i & 1);

  const int wm = wave >> 2;       // 0..1 -> C rows wm*128..+128
  const int wn = wave & 3;        // 0..3 -> C cols wn*64..+64
  const int laneRow = lane & 15;
  const int kB      = (lane >> 4) << 4;   // 0,16,32,48

  // per-thread constant byte offsets (u32; A<=33MB, B<=16MB)
  u32 aoff[8], boff[4];
#pragma unroll
  for (int mi = 0; mi < 8; ++mi)
    aoff[mi] = (u32)(mt * 256 + wm * 128 + mi * 16 + laneRow) * (u32)KDIM + (u32)kB;
#pragma unroll
  for (int ni = 0; ni < 4; ++ni)
    boff[ni] = (u32)(nt * 256 + wn * 64 + ni * 16 + laneRow) * (u32)KDIM + (u32)kB;

  i32x4 acc[8][4];
#pragma unroll
  for (int mi = 0; mi < 8; ++mi)
#pragma unroll
    for (int ni = 0; ni < 4; ++ni)
      acc[mi][ni] = i32x4{0, 0, 0, 0};

  i32x4 a0[8], b0f[4], a1[8], b1f[4];

#define LOADSET(as, bs, tt) do {                                        \
    _Pragma("unroll")                                                   \
    for (int mi = 0; mi < 8; ++mi)                                      \
      as[mi] = *(const i32x4*)(A + aoff[mi] + (tt) * BK);               \
    _Pragma("unroll")                                                   \
    for (int ni = 0; ni < 4; ++ni)                                      \
      bs[ni] = *(const i32x4*)(B + boff[ni] + (tt) * BK);               \
  } while (0)

#define MFMASET(as, bs) do {                                            \
    _Pragma("unroll")                                                   \
    for (int mi = 0; mi < 8; ++mi)                                      \
      _Pragma("unroll")                                                 \
      for (int ni = 0; ni < 4; ++ni)                                    \
        acc[mi][ni] = __builtin_amdgcn_mfma_i32_16x16x64_i8(            \
            as[mi], bs[ni], acc[mi][ni], 0, 0, 0);                      \
  } while (0)

  // prologue: tiles 0,1 in flight (24 loads)
  LOADSET(a0, b0f, 0);
  LOADSET(a1, b1f, 1);

  // main loop: t = 0..60 step 2 (issues t+2,t+3; t+3 <= 63)
  for (int t = 0; t < NKT - 2; t += 2) {
    asm volatile("s_waitcnt vmcnt(12)" ::: "memory");   // tile t landed
    MFMASET(a0, b0f);
    LOADSET(a0, b0f, t + 2);                            // reuse freed set
    asm volatile("s_waitcnt vmcnt(12)" ::: "memory");   // tile t+1 landed
    MFMASET(a1, b1f);
    LOADSET(a1, b1f, t + 3);
  }
  // tail: tiles 62, 63 (no more prefetch)
  asm volatile("s_waitcnt vmcnt(12)" ::: "memory");
  MFMASET(a0, b0f);
  asm volatile("s_waitcnt vmcnt(0)" ::: "memory");
  MFMASET(a1, b1f);

#undef LOADSET
#undef MFMASET

  // epilogue: y = acc * (xscale[row] * s[col]) + bias[col]
  const int col0 = nt * 256 + wn * 64 + (lane & 15);
  const int row0 = mt * 256 + wm * 128 + ((lane >> 4) << 2);
  float xs[4][8];
#pragma unroll
  for (int mi = 0; mi < 8; ++mi)
#pragma unroll
    for (int r = 0; r < 4; ++r)
      xs[r][mi] = xscale[row0 + mi * 16 + r];
#pragma unroll
  for (int ni = 0; ni < 4; ++ni) {
    const float sc = s[col0 + ni * 16];
    const float bv = bias[col0 + ni * 16];
#pragma unroll
    for (int mi = 0; mi < 8; ++mi) {
      float* cp = C + (size_t)(row0 + mi * 16) * NDIM + col0 + ni * 16;
#pragma unroll
      for (int r = 0; r < 4; ++r)
        cp[(size_t)r * NDIM] = (float)acc[mi][ni][r] * (xs[r][mi] * sc) + bv;
    }
  }
}

// ---------------------------------------------------------------------------
extern "C" void kernel_launch(void* const* d_in, const int* in_sizes, int n_in,
                              void* d_out, int out_size, void* d_ws, size_t ws_size,
                              hipStream_t stream) {
  (void)in_sizes; (void)n_in; (void)out_size; (void)ws_size;
  const float* x    = (const float*)d_in[0];
  const int*   Q    = (const int*)d_in[1];
  const float* s    = (const float*)d_in[2];
  const float* bias = (const float*)d_in[3];
  float* out = (float*)d_out;

  i8*    xq     = (i8*)d_ws;
  i8*    W8     = xq + (size_t)TOKENS * KDIM;
  float* xscale = (float*)(W8 + (size_t)NDIM * KDIM);

  fwht_rows_q8<<<dim3(TOKENS), dim3(64), 0, stream>>>(x, xq, xscale);
  qpack<<<dim3((NDIM * KDIM) / (256 * 16)), dim3(256), 0, stream>>>(Q, W8);
  gemm_dr_i8<<<dim3((TOKENS / 256) * (NDIM / 256)), dim3(512), 0, stream>>>(
      xq, W8, xscale, s, bias, out);
}

// Round 10
// 426.591 us; speedup vs baseline: 1.0788x; 1.0788x over previous
//
#include <hip/hip_runtime.h>
#include <hip/hip_bf16.h>

typedef int   i32x4 __attribute__((ext_vector_type(4)));
typedef unsigned int   u32;
typedef unsigned short u16;
typedef signed char    i8;

#define TOKENS 8192
#define NDIM   4096
#define KDIM   4096
#define BK     64
#define NKT    (KDIM / BK)   // 64 K-tiles
#define SLOT   32768         // A 16KB + B 16KB per ring slot

// ---------------------------------------------------------------------------
// Kernel 1 (fused): blocks 0..2047 = FWHT+int8-quant (4 rows/block, 1 wave
// per row); blocks 2048..6143 = qpack (int32 Q -> int8, 16 elems/thread).
// Both memory-bound; fusing removes a launch gap and shares HBM BW.
// ---------------------------------------------------------------------------
__device__ __forceinline__ u32 pack4(int4 q) {
  return (u32)(q.x & 0xff) | ((u32)(q.y & 0xff) << 8) |
         ((u32)(q.z & 0xff) << 16) | ((u32)(q.w & 0xff) << 24);
}

__global__ __launch_bounds__(256)
void fused_aux(const float* __restrict__ x, i8* __restrict__ xq,
               float* __restrict__ xscale,
               const int* __restrict__ Q, i8* __restrict__ W8) {
  if (blockIdx.x >= 2048) {
    // ---- qpack part ----
    const size_t idx = (((size_t)(blockIdx.x - 2048)) * 256 + threadIdx.x) * 16;
    int4 a = *reinterpret_cast<const int4*>(Q + idx);
    int4 b = *reinterpret_cast<const int4*>(Q + idx + 4);
    int4 c = *reinterpret_cast<const int4*>(Q + idx + 8);
    int4 d = *reinterpret_cast<const int4*>(Q + idx + 12);
    uint4 pk; pk.x = pack4(a); pk.y = pack4(b); pk.z = pack4(c); pk.w = pack4(d);
    *reinterpret_cast<uint4*>(W8 + idx) = pk;
    return;
  }
  // ---- FWHT part: wave w of this block does row blockIdx.x*4 + w ----
  const int row = blockIdx.x * 4 + (threadIdx.x >> 6);
  const int l   = threadIdx.x & 63;

  const float4* xv = reinterpret_cast<const float4*>(x + (size_t)row * KDIM) + l * 16;
  float v[64];
#pragma unroll
  for (int j = 0; j < 16; ++j) {
    float4 f = xv[j];
    v[4*j+0] = f.x; v[4*j+1] = f.y; v[4*j+2] = f.z; v[4*j+3] = f.w;
  }

#pragma unroll
  for (int h = 1; h < 64; h <<= 1) {
#pragma unroll
    for (int j = 0; j < 64; ++j) {
      if ((j & h) == 0) {
        float a = v[j], b = v[j + h];
        v[j] = a + b; v[j + h] = a - b;
      }
    }
  }

#pragma unroll
  for (int m = 1; m < 64; m <<= 1) {
    const bool up = (l & m) != 0;
#pragma unroll
    for (int j = 0; j < 64; ++j) {
      float p = __shfl_xor(v[j], m, 64);
      v[j] = up ? (p - v[j]) : (v[j] + p);
    }
  }

  float mxu = 0.f;
#pragma unroll
  for (int j = 0; j < 64; ++j) mxu = fmaxf(mxu, fabsf(v[j]));
#pragma unroll
  for (int m = 1; m < 64; m <<= 1) mxu = fmaxf(mxu, __shfl_xor(mxu, m, 64));
  mxu = fmaxf(mxu, 1e-30f);
  const float inv = 127.0f / mxu;

  i8* orow = xq + (size_t)row * KDIM + l * 64;
#pragma unroll
  for (int g = 0; g < 4; ++g) {
    u32 w[4];
#pragma unroll
    for (int q4 = 0; q4 < 4; ++q4) {
      int b0 = __float2int_rn(v[g*16+q4*4+0] * inv);
      int b1 = __float2int_rn(v[g*16+q4*4+1] * inv);
      int b2 = __float2int_rn(v[g*16+q4*4+2] * inv);
      int b3 = __float2int_rn(v[g*16+q4*4+3] * inv);
      b0 = min(127, max(-127, b0)); b1 = min(127, max(-127, b1));
      b2 = min(127, max(-127, b2)); b3 = min(127, max(-127, b3));
      w[q4] = (u32)(b0 & 0xff) | ((u32)(b1 & 0xff) << 8) |
              ((u32)(b2 & 0xff) << 16) | ((u32)(b3 & 0xff) << 24);
    }
    uint4 pk; pk.x = w[0]; pk.y = w[1]; pk.z = w[2]; pk.w = w[3];
    *reinterpret_cast<uint4*>(orow + g * 16) = pk;
  }
  if (l == 0) xscale[row] = mxu * (0.015625f / 127.0f);
}

// ---------------------------------------------------------------------------
// Kernel 2: int8 GEMM, 4 waves x (128x128 per wave) => LDS reads cut 96->64 KB
// per 256^2 tile (fatter wave-tiles = less fragment duplication).
// BM=BN=256, BK=64, 256 threads, acc[8][8] (256 AGPR, ~380 regs -> 1 wave/SIMD).
// Ring-3 slots (96 KB), counted lgkm(4)/lgkm(12), vmcnt(8), 1 barrier/tile.
// Verified XOR swizzle and pre-swizzled staging sources (conflict-free, R4-R8).
// ---------------------------------------------------------------------------
__global__ __launch_bounds__(256, 1)
void gemm_w4(const i8* __restrict__ A, const i8* __restrict__ B,
             const float* __restrict__ xscale, const float* __restrict__ s,
             const float* __restrict__ bias, float* __restrict__ C) {
  __shared__ __align__(16) i8 lds[3 * SLOT];   // 96 KB

  const int th   = threadIdx.x;
  const int wave = th >> 6;
  const int lane = th & 63;

  // L2-locality mapping (bijective, 512 blocks)
  const int b0 = blockIdx.x;
  const int xc = b0 & 7;
  const int i  = b0 >> 3;
  const int mt = i >> 1;
  const int nt = xc * 2 + (i & 1);

  // staging: 256 threads, 8 loads each (A j=0..3, B j=0..3).
  // load j covers rows j*64 + (th>>2); 16 B at pre-swizzled column.
  const int srow = th >> 2;
  const int scol = ((th & 3) * 16) ^ (((th >> 5) & 1) << 5);
  const i8* gA[4]; const i8* gB[4];
#pragma unroll
  for (int j = 0; j < 4; ++j) {
    gA[j] = A + (size_t)(mt * 256 + j * 64 + srow) * KDIM + scol;
    gB[j] = B + (size_t)(nt * 256 + j * 64 + srow) * KDIM + scol;
  }
  const int ldsW = wave * 1024;  // wave-uniform lane base within a 4096-B j-chunk

#define STAGE(tt, ss) do {                                                        \
    _Pragma("unroll")                                                             \
    for (int j = 0; j < 4; ++j)                                                   \
      __builtin_amdgcn_global_load_lds(                                           \
        (const __attribute__((address_space(1))) void*)(gA[j] + (size_t)(tt) * BK), \
        (__attribute__((address_space(3))) void*)(lds + (ss) * SLOT + j * 4096 + ldsW), 16, 0, 0); \
    _Pragma("unroll")                                                             \
    for (int j = 0; j < 4; ++j)                                                   \
      __builtin_amdgcn_global_load_lds(                                           \
        (const __attribute__((address_space(1))) void*)(gB[j] + (size_t)(tt) * BK), \
        (__attribute__((address_space(3))) void*)(lds + (ss) * SLOT + 16384 + j * 4096 + ldsW), 16, 0, 0); \
  } while (0)

  // fragment read offsets (bytes within slot); same verified XOR swizzle
  const int wm = wave >> 1;       // 0..1 -> C rows wm*128
  const int wn = wave & 1;        // 0..1 -> C cols wn*128
  const int laneRow = lane & 15;
  const int kByte   = (lane >> 4) << 4;
  const int swz     = ((lane >> 3) & 1) << 5;
  const int aOff = (((wm * 128 + laneRow) * 64 + kByte) ^ swz);          // + mi*1024
  const int bOff = (((wn * 128 + laneRow) * 64 + kByte) ^ swz) + 16384;  // + ni*1024

  i32x4 acc[8][8];
#pragma unroll
  for (int mi = 0; mi < 8; ++mi)
#pragma unroll
    for (int ni = 0; ni < 8; ++ni)
      acc[mi][ni] = i32x4{0, 0, 0, 0};

  i32x4 afA[4], afB[4], bf0[8], bf1[8];

  // prologue: stage tiles 0,1 into slots 0,1; wait tile 0; preload its frags
  STAGE(0, 0);
  STAGE(1, 1);
  asm volatile("s_waitcnt vmcnt(8)" ::: "memory");
  __builtin_amdgcn_sched_barrier(0);
  __builtin_amdgcn_s_barrier();
  {
    const char* c0 = (const char*)lds;
#pragma unroll
    for (int ni = 0; ni < 8; ++ni)
      bf0[ni] = *(const i32x4*)(c0 + bOff + ni * 1024);
#pragma unroll
    for (int mi = 0; mi < 4; ++mi)
      afA[mi] = *(const i32x4*)(c0 + aOff + mi * 1024);
  }

  int sCur = 0, sNxt = 1, sStg = 2;

#define TILE(t, BFC, BFN) do {                                                    \
    const char* cur = (const char*)lds + sCur * SLOT;                             \
    const char* nxt = (const char*)lds + sNxt * SLOT;                             \
    _Pragma("unroll")                                                             \
    for (int mi = 0; mi < 4; ++mi)                                                \
      afB[mi] = *(const i32x4*)(cur + aOff + 4096 + mi * 1024);                   \
    if ((t) + 2 < NKT) STAGE((t) + 2, sStg);                                      \
    asm volatile("s_waitcnt lgkmcnt(4)" ::: "memory");  /* afA + BFC ready */     \
    __builtin_amdgcn_sched_barrier(0);                                            \
    __builtin_amdgcn_s_setprio(1);                                                \
    _Pragma("unroll")                                                             \
    for (int mi = 0; mi < 4; ++mi)                                                \
      _Pragma("unroll")                                                           \
      for (int ni = 0; ni < 8; ++ni)                                              \
        acc[mi][ni] = __builtin_amdgcn_mfma_i32_16x16x64_i8(afA[mi], BFC[ni],     \
                                                            acc[mi][ni], 0, 0, 0); \
    __builtin_amdgcn_s_setprio(0);                                                \
    if ((t) + 2 < NKT)      { asm volatile("s_waitcnt vmcnt(8)" ::: "memory"); }  \
    else if ((t) + 1 < NKT) { asm volatile("s_waitcnt vmcnt(0)" ::: "memory"); }  \
    __builtin_amdgcn_sched_barrier(0);                                            \
    if ((t) + 1 < NKT) {                                                          \
      __builtin_amdgcn_s_barrier();   /* tile t+1 staged, slot rotation safe */   \
      _Pragma("unroll")                                                           \
      for (int ni = 0; ni < 8; ++ni)                                              \
        BFN[ni] = *(const i32x4*)(nxt + bOff + ni * 1024);                        \
      _Pragma("unroll")                                                           \
      for (int mi = 0; mi < 4; ++mi)                                              \
        afA[mi] = *(const i32x4*)(nxt + aOff + mi * 1024);                        \
      asm volatile("s_waitcnt lgkmcnt(12)" ::: "memory");  /* afB ready */        \
      __builtin_amdgcn_sched_barrier(0);                                          \
    } else {                                                                      \
      asm volatile("s_waitcnt lgkmcnt(0)" ::: "memory");                          \
      __builtin_amdgcn_sched_barrier(0);                                          \
    }                                                                             \
    __builtin_amdgcn_s_setprio(1);                                                \
    _Pragma("unroll")                                                             \
    for (int mi = 0; mi < 4; ++mi)                                                \
      _Pragma("unroll")                                                           \
      for (int ni = 0; ni < 8; ++ni)                                              \
        acc[mi + 4][ni] = __builtin_amdgcn_mfma_i32_16x16x64_i8(afB[mi], BFC[ni], \
                                                        acc[mi + 4][ni], 0, 0, 0); \
    __builtin_amdgcn_s_setprio(0);                                                \
    int _tmp = sCur; sCur = sNxt; sNxt = sStg; sStg = _tmp;                       \
  } while (0)

  for (int t = 0; t < NKT; t += 2) {
    TILE(t,     bf0, bf1);
    TILE(t + 1, bf1, bf0);
  }
#undef TILE
#undef STAGE

  // epilogue: y = acc * (xscale[row] * s[col]) + bias[col]
  const int col0 = nt * 256 + wn * 128 + (lane & 15);
  const int row0 = mt * 256 + wm * 128 + ((lane >> 4) << 2);
  float xs[4][8];
#pragma unroll
  for (int mi = 0; mi < 8; ++mi)
#pragma unroll
    for (int r = 0; r < 4; ++r)
      xs[r][mi] = xscale[row0 + mi * 16 + r];
#pragma unroll
  for (int ni = 0; ni < 8; ++ni) {
    const float sc = s[col0 + ni * 16];
    const float bv = bias[col0 + ni * 16];
#pragma unroll
    for (int mi = 0; mi < 8; ++mi) {
      float* cp = C + (size_t)(row0 + mi * 16) * NDIM + col0 + ni * 16;
#pragma unroll
      for (int r = 0; r < 4; ++r)
        cp[(size_t)r * NDIM] = (float)acc[mi][ni][r] * (xs[r][mi] * sc) + bv;
    }
  }
}

// ---------------------------------------------------------------------------
extern "C" void kernel_launch(void* const* d_in, const int* in_sizes, int n_in,
                              void* d_out, int out_size, void* d_ws, size_t ws_size,
                              hipStream_t stream) {
  (void)in_sizes; (void)n_in; (void)out_size; (void)ws_size;
  const float* x    = (const float*)d_in[0];
  const int*   Q    = (const int*)d_in[1];
  const float* s    = (const float*)d_in[2];
  const float* bias = (const float*)d_in[3];
  float* out = (float*)d_out;

  i8*    xq     = (i8*)d_ws;                            // [8192][4096] int8
  i8*    W8     = xq + (size_t)TOKENS * KDIM;           // [4096][4096] int8
  float* xscale = (float*)(W8 + (size_t)NDIM * KDIM);   // [8192] f32

  fused_aux<<<dim3(6144), dim3(256), 0, stream>>>(x, xq, xscale, Q, W8);
  gemm_w4<<<dim3((TOKENS / 256) * (NDIM / 256)), dim3(256), 0, stream>>>(
      xq, W8, xscale, s, bias, out);
}

// Round 11
// 196.584 us; speedup vs baseline: 2.3410x; 2.1700x over previous
//
#include <hip/hip_runtime.h>
#include <hip/hip_bf16.h>

typedef int   i32x4 __attribute__((ext_vector_type(4)));
typedef unsigned int   u32;
typedef unsigned short u16;
typedef signed char    i8;

#define TOKENS 8192
#define NDIM   4096
#define KDIM   4096
#define BK     64
#define NKT    (KDIM / BK)   // 64 K-tiles
#define SLOT   32768

// ---------------------------------------------------------------------------
// Kernel 1 (fused, validated R10): blocks 0..2047 FWHT+q8; 2048..6143 qpack.
// ---------------------------------------------------------------------------
__device__ __forceinline__ u32 pack4(int4 q) {
  return (u32)(q.x & 0xff) | ((u32)(q.y & 0xff) << 8) |
         ((u32)(q.z & 0xff) << 16) | ((u32)(q.w & 0xff) << 24);
}

__global__ __launch_bounds__(256)
void fused_aux(const float* __restrict__ x, i8* __restrict__ xq,
               float* __restrict__ xscale,
               const int* __restrict__ Q, i8* __restrict__ W8) {
  if (blockIdx.x >= 2048) {
    const size_t idx = (((size_t)(blockIdx.x - 2048)) * 256 + threadIdx.x) * 16;
    int4 a = *reinterpret_cast<const int4*>(Q + idx);
    int4 b = *reinterpret_cast<const int4*>(Q + idx + 4);
    int4 c = *reinterpret_cast<const int4*>(Q + idx + 8);
    int4 d = *reinterpret_cast<const int4*>(Q + idx + 12);
    uint4 pk; pk.x = pack4(a); pk.y = pack4(b); pk.z = pack4(c); pk.w = pack4(d);
    *reinterpret_cast<uint4*>(W8 + idx) = pk;
    return;
  }
  const int row = blockIdx.x * 4 + (threadIdx.x >> 6);
  const int l   = threadIdx.x & 63;

  const float4* xv = reinterpret_cast<const float4*>(x + (size_t)row * KDIM) + l * 16;
  float v[64];
#pragma unroll
  for (int j = 0; j < 16; ++j) {
    float4 f = xv[j];
    v[4*j+0] = f.x; v[4*j+1] = f.y; v[4*j+2] = f.z; v[4*j+3] = f.w;
  }

#pragma unroll
  for (int h = 1; h < 64; h <<= 1) {
#pragma unroll
    for (int j = 0; j < 64; ++j) {
      if ((j & h) == 0) {
        float a = v[j], b = v[j + h];
        v[j] = a + b; v[j + h] = a - b;
      }
    }
  }

#pragma unroll
  for (int m = 1; m < 64; m <<= 1) {
    const bool up = (l & m) != 0;
#pragma unroll
    for (int j = 0; j < 64; ++j) {
      float p = __shfl_xor(v[j], m, 64);
      v[j] = up ? (p - v[j]) : (v[j] + p);
    }
  }

  float mxu = 0.f;
#pragma unroll
  for (int j = 0; j < 64; ++j) mxu = fmaxf(mxu, fabsf(v[j]));
#pragma unroll
  for (int m = 1; m < 64; m <<= 1) mxu = fmaxf(mxu, __shfl_xor(mxu, m, 64));
  mxu = fmaxf(mxu, 1e-30f);
  const float inv = 127.0f / mxu;

  i8* orow = xq + (size_t)row * KDIM + l * 64;
#pragma unroll
  for (int g = 0; g < 4; ++g) {
    u32 w[4];
#pragma unroll
    for (int q4 = 0; q4 < 4; ++q4) {
      int b0 = __float2int_rn(v[g*16+q4*4+0] * inv);
      int b1 = __float2int_rn(v[g*16+q4*4+1] * inv);
      int b2 = __float2int_rn(v[g*16+q4*4+2] * inv);
      int b3 = __float2int_rn(v[g*16+q4*4+3] * inv);
      b0 = min(127, max(-127, b0)); b1 = min(127, max(-127, b1));
      b2 = min(127, max(-127, b2)); b3 = min(127, max(-127, b3));
      w[q4] = (u32)(b0 & 0xff) | ((u32)(b1 & 0xff) << 8) |
              ((u32)(b2 & 0xff) << 16) | ((u32)(b3 & 0xff) << 24);
    }
    uint4 pk; pk.x = w[0]; pk.y = w[1]; pk.z = w[2]; pk.w = w[3];
    *reinterpret_cast<uint4*>(orow + g * 16) = pk;
  }
  if (l == 0) xscale[row] = mxu * (0.015625f / 127.0f);
}

// ---------------------------------------------------------------------------
// Kernel 2: int8 GEMM, R6 geometry + DEEP-LEAD pipeline (2-tile stage lead).
// BM=BN=256, BK=64, 8 waves (2Mx4N), per-wave 128x64 (acc[8][4], ~104 VGPR),
// ring-4 slots: compute t | read-ahead t+1 | staged t+2 | staging t+3.
// Per tile, ONE barrier:
//   afB reads(4) -> lgkm(4) -> MFMA half0 -> vmcnt(4) [t+1 landed, lead=2
//   tiles covers HBM latency; t+2 stays in flight] -> barrier ->
//   STAGE(t+3) into slot (t-1)&3 [dead: all waves drained t-1 reads] ->
//   bf/afA reads(8) of t+1 -> lgkm(8) -> MFMA half1.
// Waits never 0 mid-loop; sched_barrier(0) after each inline wait (rule 18).
// ---------------------------------------------------------------------------
__global__ __launch_bounds__(512, 2)
void gemm_i8_dp(const i8* __restrict__ A, const i8* __restrict__ B,
                const float* __restrict__ xscale, const float* __restrict__ s,
                const float* __restrict__ bias, float* __restrict__ C) {
  __shared__ __align__(16) i8 lds[4 * SLOT];   // 128 KB

  const int th   = threadIdx.x;
  const int wave = th >> 6;
  const int lane = th & 63;

  // L2-locality mapping (bijective, 512 blocks)
  const int b0 = blockIdx.x;
  const int xc = b0 & 7;
  const int i  = b0 >> 3;
  const int mt = i >> 1;
  const int nt = xc * 2 + (i & 1);

  const int srow = th >> 2;
  const int scol = ((th & 3) * 16) ^ (((th >> 5) & 1) << 5);
  const i8* gA0 = A + (size_t)(mt * 256 + srow) * KDIM + scol;
  const i8* gA1 = gA0 + (size_t)128 * KDIM;
  const i8* gB0 = B + (size_t)(nt * 256 + srow) * KDIM + scol;
  const i8* gB1 = gB0 + (size_t)128 * KDIM;

  const int ldsA0 = wave * 1024;
  const int ldsA1 = 8192 + wave * 1024;
  const int ldsB0 = 16384 + wave * 1024;
  const int ldsB1 = 24576 + wave * 1024;

#define STAGE(tt, ss) do {                                                      \
    __builtin_amdgcn_global_load_lds(                                           \
      (const __attribute__((address_space(1))) void*)(gA0 + (size_t)(tt) * BK), \
      (__attribute__((address_space(3))) void*)(lds + (ss) * SLOT + ldsA0), 16, 0, 0); \
    __builtin_amdgcn_global_load_lds(                                           \
      (const __attribute__((address_space(1))) void*)(gA1 + (size_t)(tt) * BK), \
      (__attribute__((address_space(3))) void*)(lds + (ss) * SLOT + ldsA1), 16, 0, 0); \
    __builtin_amdgcn_global_load_lds(                                           \
      (const __attribute__((address_space(1))) void*)(gB0 + (size_t)(tt) * BK), \
      (__attribute__((address_space(3))) void*)(lds + (ss) * SLOT + ldsB0), 16, 0, 0); \
    __builtin_amdgcn_global_load_lds(                                           \
      (const __attribute__((address_space(1))) void*)(gB1 + (size_t)(tt) * BK), \
      (__attribute__((address_space(3))) void*)(lds + (ss) * SLOT + ldsB1), 16, 0, 0); \
  } while (0)

  const int wm = wave >> 2;
  const int wn = wave & 3;
  const int laneRow = lane & 15;
  const int kByte   = (lane >> 4) << 4;
  const int swz     = ((lane >> 3) & 1) << 5;
  const int aOff = (((wm * 128 + laneRow) * 64 + kByte) ^ swz);
  const int bOff = (((wn * 64 + laneRow) * 64 + kByte) ^ swz) + 16384;

  i32x4 acc[8][4];
#pragma unroll
  for (int mi = 0; mi < 8; ++mi)
#pragma unroll
    for (int ni = 0; ni < 4; ++ni)
      acc[mi][ni] = i32x4{0, 0, 0, 0};

  // prologue: stage 0,1,2 (12 gloads); wait tile 0 (8 newest fly); preload.
  STAGE(0, 0); STAGE(1, 1); STAGE(2, 2);
  asm volatile("s_waitcnt vmcnt(8)" ::: "memory");
  __builtin_amdgcn_sched_barrier(0);
  __builtin_amdgcn_s_barrier();

  i32x4 afA[4], afB[4], bf0[4], bf1[4];
  {
    const char* c0 = (const char*)lds;
#pragma unroll
    for (int ni = 0; ni < 4; ++ni)
      bf0[ni] = *(const i32x4*)(c0 + bOff + ni * 1024);
#pragma unroll
    for (int mi = 0; mi < 4; ++mi)
      afA[mi] = *(const i32x4*)(c0 + aOff + mi * 1024);
  }

#define TILE(t, BFC, BFN) do {                                                  \
    const char* cur = (const char*)lds + ((t) & 3) * SLOT;                      \
    const char* nxt = (const char*)lds + (((t) + 1) & 3) * SLOT;                \
    _Pragma("unroll")                                                           \
    for (int mi = 0; mi < 4; ++mi)                                              \
      afB[mi] = *(const i32x4*)(cur + aOff + 4096 + mi * 1024);                 \
    asm volatile("s_waitcnt lgkmcnt(4)" ::: "memory");  /* afA+BFC ready */     \
    __builtin_amdgcn_sched_barrier(0);                                          \
    __builtin_amdgcn_s_setprio(1);                                              \
    _Pragma("unroll")                                                           \
    for (int mi = 0; mi < 4; ++mi)                                              \
      _Pragma("unroll")                                                         \
      for (int ni = 0; ni < 4; ++ni)                                            \
        acc[mi][ni] = __builtin_amdgcn_mfma_i32_16x16x64_i8(afA[mi], BFC[ni],   \
                                                            acc[mi][ni], 0, 0, 0); \
    __builtin_amdgcn_s_setprio(0);                                              \
    if ((t) + 2 < NKT)      { asm volatile("s_waitcnt vmcnt(4)" ::: "memory"); } \
    else if ((t) + 1 < NKT) { asm volatile("s_waitcnt vmcnt(0)" ::: "memory"); } \
    __builtin_amdgcn_sched_barrier(0);                                          \
    __builtin_amdgcn_s_barrier();                                               \
    if ((t) + 3 < NKT) STAGE((t) + 3, ((t) + 3) & 3);                           \
    if ((t) + 1 < NKT) {                                                        \
      _Pragma("unroll")                                                         \
      for (int ni = 0; ni < 4; ++ni)                                            \
        BFN[ni] = *(const i32x4*)(nxt + bOff + ni * 1024);                      \
      _Pragma("unroll")                                                         \
      for (int mi = 0; mi < 4; ++mi)                                            \
        afA[mi] = *(const i32x4*)(nxt + aOff + mi * 1024);                      \
      asm volatile("s_waitcnt lgkmcnt(8)" ::: "memory");  /* afB ready */       \
    } else {                                                                    \
      asm volatile("s_waitcnt lgkmcnt(0)" ::: "memory");                        \
    }                                                                           \
    __builtin_amdgcn_sched_barrier(0);                                          \
    __builtin_amdgcn_s_setprio(1);                                              \
    _Pragma("unroll")                                                           \
    for (int mi = 0; mi < 4; ++mi)                                              \
      _Pragma("unroll")                                                         \
      for (int ni = 0; ni < 4; ++ni)                                            \
        acc[mi + 4][ni] = __builtin_amdgcn_mfma_i32_16x16x64_i8(afB[mi], BFC[ni], \
                                                        acc[mi + 4][ni], 0, 0, 0); \
    __builtin_amdgcn_s_setprio(0);                                              \
  } while (0)

  for (int t = 0; t < NKT; t += 2) {
    TILE(t,     bf0, bf1);
    TILE(t + 1, bf1, bf0);
  }
#undef TILE
#undef STAGE

  // epilogue: y = acc * (xscale[row] * s[col]) + bias[col]
  const int col0 = nt * 256 + wn * 64 + (lane & 15);
  const int row0 = mt * 256 + wm * 128 + ((lane >> 4) << 2);
  float xs[4][8];
#pragma unroll
  for (int mi = 0; mi < 8; ++mi)
#pragma unroll
    for (int r = 0; r < 4; ++r)
      xs[r][mi] = xscale[row0 + mi * 16 + r];
#pragma unroll
  for (int ni = 0; ni < 4; ++ni) {
    const float sc = s[col0 + ni * 16];
    const float bv = bias[col0 + ni * 16];
#pragma unroll
    for (int mi = 0; mi < 8; ++mi) {
      float* cp = C + (size_t)(row0 + mi * 16) * NDIM + col0 + ni * 16;
#pragma unroll
      for (int r = 0; r < 4; ++r)
        cp[(size_t)r * NDIM] = (float)acc[mi][ni][r] * (xs[r][mi] * sc) + bv;
    }
  }
}

// ---------------------------------------------------------------------------
extern "C" void kernel_launch(void* const* d_in, const int* in_sizes, int n_in,
                              void* d_out, int out_size, void* d_ws, size_t ws_size,
                              hipStream_t stream) {
  (void)in_sizes; (void)n_in; (void)out_size; (void)ws_size;
  const float* x    = (const float*)d_in[0];
  const int*   Q    = (const int*)d_in[1];
  const float* s    = (const float*)d_in[2];
  const float* bias = (const float*)d_in[3];
  float* out = (float*)d_out;

  i8*    xq     = (i8*)d_ws;
  i8*    W8     = xq + (size_t)TOKENS * KDIM;
  float* xscale = (float*)(W8 + (size_t)NDIM * KDIM);

  fused_aux<<<dim3(6144), dim3(256), 0, stream>>>(x, xq, xscale, Q, W8);
  gemm_i8_dp<<<dim3((TOKENS / 256) * (NDIM / 256)), dim3(512), 0, stream>>>(
      xq, W8, xscale, s, bias, out);
}